// Round 1
// baseline (3051.568 us; speedup 1.0000x reference)
//
#include <hip/hip_runtime.h>

// TitansMemory: per-row delta-rule-with-momentum scan.
// B=16, L=8192, DK=DV=128.  2048 independent rows (b, v); each row:
//   resid = w·k - v ; m̂ = β m̂ + ŝ k (ŝ = -2 lr (1-β) resid, m̂ = -lr m)
//   w = (1-α) w + m̂ ; y = w·q
// Mapping: 16 lanes per row (one DPP row), 8 cols/lane, 4 rows/wave,
// 512 waves = 512 blocks × 64 threads (2 waves/CU). DPP row_ror reductions
// keep the cross-lane sum off the LDS pipe. 4-step register prefetch of k/q/v.

#define B_ 16
#define L_ 8192
#define D_ 128

// Constants matched to the f32 reference arithmetic:
// (1-ALPHA)=0.98, BETA=0.9, -2*LR*(1-BETA) with LR=0.1, (1-BETA)->f32(0.1)
__constant__ constexpr float A_    = 0.98f;
__constant__ constexpr float BETA_ = 0.9f;
__constant__ constexpr float C_S   = -(2.0f * 0.1f * 0.1f);

struct Frag {
  float4 k0, k1, q0, q1;
  float v;
};

__device__ __forceinline__ Frag load_frag(const float* __restrict__ Kp,
                                          const float* __restrict__ Qp,
                                          const float* __restrict__ Vp,
                                          int t) {
  int tl = (t < L_) ? t : (L_ - 1);   // clamp prefetch past the end
  const float* kp = Kp + (size_t)tl * D_;
  const float* qp = Qp + (size_t)tl * D_;
  Frag f;
  f.k0 = *(const float4*)(kp);
  f.k1 = *(const float4*)(kp + 4);
  f.q0 = *(const float4*)(qp);
  f.q1 = *(const float4*)(qp + 4);
  f.v  = Vp[(size_t)tl * D_];
  return f;
}

template <int CTRL>
__device__ __forceinline__ float dpp_add(float x) {
  int y = __builtin_amdgcn_update_dpp(0, __float_as_int(x), CTRL, 0xF, 0xF, true);
  return x + __int_as_float(y);
}

// Sum across each 16-lane DPP row; every lane of the row gets the total.
// row_ror:1,2,4,8 circulant reduction — pure VALU latency, no LDS pipe.
__device__ __forceinline__ float row16_allsum(float x) {
  x = dpp_add<0x121>(x);  // row_ror:1
  x = dpp_add<0x122>(x);  // row_ror:2
  x = dpp_add<0x124>(x);  // row_ror:4
  x = dpp_add<0x128>(x);  // row_ror:8
  return x;
}

__device__ __forceinline__ void step_fn(const Frag& f,
                                        float4& w0, float4& w1,
                                        float4& m0, float4& m1,
                                        float* __restrict__ yaddr,
                                        bool do_store) {
  // ---- resid = w·k - v  (on the serial chain) ----
  float a0 = w0.x * f.k0.x;
  float a1 = w0.y * f.k0.y;
  float a2 = w0.z * f.k0.z;
  float a3 = w0.w * f.k0.w;
  a0 = fmaf(w1.x, f.k1.x, a0);
  a1 = fmaf(w1.y, f.k1.y, a1);
  a2 = fmaf(w1.z, f.k1.z, a2);
  a3 = fmaf(w1.w, f.k1.w, a3);
  float dot = row16_allsum((a0 + a1) + (a2 + a3));
  float s = C_S * (dot - f.v);

  // ---- m̂ = β m̂ + s k ; w = A w + m̂  (3 VALU per element) ----
  m0.x = fmaf(BETA_, m0.x, s * f.k0.x);
  m0.y = fmaf(BETA_, m0.y, s * f.k0.y);
  m0.z = fmaf(BETA_, m0.z, s * f.k0.z);
  m0.w = fmaf(BETA_, m0.w, s * f.k0.w);
  m1.x = fmaf(BETA_, m1.x, s * f.k1.x);
  m1.y = fmaf(BETA_, m1.y, s * f.k1.y);
  m1.z = fmaf(BETA_, m1.z, s * f.k1.z);
  m1.w = fmaf(BETA_, m1.w, s * f.k1.w);

  w0.x = fmaf(A_, w0.x, m0.x);
  w0.y = fmaf(A_, w0.y, m0.y);
  w0.z = fmaf(A_, w0.z, m0.z);
  w0.w = fmaf(A_, w0.w, m0.w);
  w1.x = fmaf(A_, w1.x, m1.x);
  w1.y = fmaf(A_, w1.y, m1.y);
  w1.z = fmaf(A_, w1.z, m1.z);
  w1.w = fmaf(A_, w1.w, m1.w);

  // ---- y = w·q  (off the serial chain) ----
  float b0 = w0.x * f.q0.x;
  float b1 = w0.y * f.q0.y;
  float b2 = w0.z * f.q0.z;
  float b3 = w0.w * f.q0.w;
  b0 = fmaf(w1.x, f.q1.x, b0);
  b1 = fmaf(w1.y, f.q1.y, b1);
  b2 = fmaf(w1.z, f.q1.z, b2);
  b3 = fmaf(w1.w, f.q1.w, b3);
  float y = row16_allsum((b0 + b1) + (b2 + b3));

  if (do_store) *yaddr = y;
}

__global__ __launch_bounds__(64, 1)
void TitansMemory_188978561365_kernel(const float* __restrict__ Q,
                                      const float* __restrict__ K,
                                      const float* __restrict__ V,
                                      float* __restrict__ Y) {
  const int wid   = blockIdx.x;        // 0..511
  const int lane  = threadIdx.x;       // 0..63
  const int batch = wid >> 5;          // 32 waves per batch
  const int rowbase = (wid & 31) << 2; // 4 rows per wave
  const int rl   = lane >> 4;          // row within wave (DPP row id)
  const int c16  = lane & 15;          // column group
  const int col0 = c16 << 3;           // 8 cols per lane
  const int row  = rowbase + rl;

  const size_t bbase = (size_t)batch * L_ * D_;
  const float* Kp = K + bbase + col0;
  const float* Qp = Q + bbase + col0;
  const float* Vp = V + bbase + row;
  float*       Yp = Y + bbase + row;
  const bool do_store = (c16 == 0);

  float4 w0 = {0.f, 0.f, 0.f, 0.f}, w1 = {0.f, 0.f, 0.f, 0.f};
  float4 m0 = {0.f, 0.f, 0.f, 0.f}, m1 = {0.f, 0.f, 0.f, 0.f};

  // 4-deep register prefetch to cover L2/HBM latency.
  Frag f0 = load_frag(Kp, Qp, Vp, 0);
  Frag f1 = load_frag(Kp, Qp, Vp, 1);
  Frag f2 = load_frag(Kp, Qp, Vp, 2);
  Frag f3 = load_frag(Kp, Qp, Vp, 3);

  for (int t = 0; t < L_; t += 4) {
    step_fn(f0, w0, w1, m0, m1, Yp + (size_t)(t + 0) * D_, do_store);
    f0 = load_frag(Kp, Qp, Vp, t + 4);
    step_fn(f1, w0, w1, m0, m1, Yp + (size_t)(t + 1) * D_, do_store);
    f1 = load_frag(Kp, Qp, Vp, t + 5);
    step_fn(f2, w0, w1, m0, m1, Yp + (size_t)(t + 2) * D_, do_store);
    f2 = load_frag(Kp, Qp, Vp, t + 6);
    step_fn(f3, w0, w1, m0, m1, Yp + (size_t)(t + 3) * D_, do_store);
    f3 = load_frag(Kp, Qp, Vp, t + 7);
  }
}

extern "C" void kernel_launch(void* const* d_in, const int* in_sizes, int n_in,
                              void* d_out, int out_size, void* d_ws, size_t ws_size,
                              hipStream_t stream) {
  const float* Q = (const float*)d_in[0];
  const float* K = (const float*)d_in[1];
  const float* V = (const float*)d_in[2];
  float* Y = (float*)d_out;
  dim3 grid(512), block(64);
  hipLaunchKernelGGL(TitansMemory_188978561365_kernel, grid, block, 0, stream,
                     Q, K, V, Y);
}

// Round 2
// 2189.340 us; speedup vs baseline: 1.3938x; 1.3938x over previous
//
#include <hip/hip_runtime.h>

// TitansMemory: per-row delta-rule-with-momentum scan. B=16, L=8192, DK=DV=128.
// 2048 independent rows (b,v):
//   resid = w·k - v ; m̂ = β m̂ + s k (s = -2 lr (1-β) resid, m̂ = -lr m)
//   w = (1-α) w + m̂ ; y = w·q
// Mapping: 16 lanes/row (one DPP row), 8 cols/lane, 4 rows/wave, 512 waves
// = 512 single-wave blocks (no __syncthreads needed). DPP row_ror reductions
// keep the cross-lane sum off the LDS pipe.
// Memory: double-buffered LDS chunks of T=16 steps. Per chunk iteration:
//   ds_write chunk c+1 (from regs loaded LAST iteration -> uncollapsible
//   loop-carried prefetch distance ~2200 cyc), issue global loads for chunk
//   c+2, compute 16 steps from chunk c. XOR slot swizzle keeps b128 LDS reads
//   at free 2-way aliasing. 1-step register frag prefetch covers LDS latency.

#define B_ 16
#define L_ 8192
#define D_ 128
#define T_ 16
#define NCH (L_ / T_)

constexpr float A_    = 0.98f;
constexpr float BETA_ = 0.9f;
constexpr float C_S   = -(2.0f * 0.1f * 0.1f);

template <int CTRL>
__device__ __forceinline__ float dpp_add(float x) {
  int y = __builtin_amdgcn_update_dpp(0, __float_as_int(x), CTRL, 0xF, 0xF, true);
  return x + __int_as_float(y);
}

// Sum across each 16-lane DPP row; every lane of the row gets the total.
__device__ __forceinline__ float row16_allsum(float x) {
  x = dpp_add<0x121>(x);  // row_ror:1
  x = dpp_add<0x122>(x);  // row_ror:2
  x = dpp_add<0x124>(x);  // row_ror:4
  x = dpp_add<0x128>(x);  // row_ror:8
  return x;
}

struct Frag {
  float4 k0, k1, q0, q1;
  float v;
};

__device__ __forceinline__ int permslot(int s) { return s ^ ((s >> 3) & 7); }

__global__ __launch_bounds__(64)
void TitansMemory_188978561365_kernel(const float* __restrict__ Q,
                                      const float* __restrict__ K,
                                      const float* __restrict__ V,
                                      float* __restrict__ Y) {
  // kq staging: per t-row, 64 float4 slots: slots 0..31 = k cols s*4..s*4+3,
  // slots 32..63 = q cols (s-32)*4.. ; stored at permuted slot.
  __shared__ float4 skq[2][T_][64];
  __shared__ float  sv[2][64];   // [t*4 + r] for rows rowbase+r

  const int lane  = threadIdx.x;       // 0..63
  const int wid   = blockIdx.x;        // 0..511
  const int batch = wid >> 5;          // 32 waves per batch
  const int rowbase = (wid & 31) << 2; // 4 rows per wave
  const int rl   = lane >> 4;          // row within wave (DPP row id)
  const int c16  = lane & 15;          // column group (8 cols per lane)

  const size_t bbase = (size_t)batch * (size_t)L_ * D_;

  // Staging: lane l loads slot l of each t-row (k for l<32, q for l>=32).
  const float* gsrc = (lane < 32) ? (K + bbase + lane * 4)
                                  : (Q + bbase + (lane - 32) * 4);
  const float* vsrc = V + bbase + rowbase + (lane & 3);
  const int vt_off  = lane >> 2;       // t-within-chunk this lane stages for v

  const int wslot = permslot(lane);
  const int pk0 = permslot(2 * c16);
  const int pk1 = permslot(2 * c16 + 1);
  const int pq0 = permslot(32 + 2 * c16);
  const int pq1 = permslot(33 + 2 * c16);

  float* Yp = Y + bbase + rowbase + rl;
  const bool do_store = (c16 == 0);

  float4 st[T_];
  float  stv;

  auto load_stage = [&](int t0) {
#pragma unroll
    for (int j = 0; j < T_; ++j) {
      int t = t0 + j;
      t = (t < L_) ? t : (L_ - 1);     // clamp (tail chunks never computed)
      st[j] = *(const float4*)(gsrc + (size_t)t * D_);
    }
    int tv = t0 + vt_off;
    tv = (tv < L_) ? tv : (L_ - 1);
    stv = vsrc[(size_t)tv * D_];
  };

  auto write_stage = [&](int bsel) {
#pragma unroll
    for (int j = 0; j < T_; ++j) skq[bsel][j][wslot] = st[j];
    sv[bsel][lane] = stv;
  };

  auto read_frag = [&](int bsel, int t) {
    Frag f;
    f.k0 = skq[bsel][t][pk0];
    f.k1 = skq[bsel][t][pk1];
    f.q0 = skq[bsel][t][pq0];
    f.q1 = skq[bsel][t][pq1];
    f.v  = sv[bsel][t * 4 + rl];
    return f;
  };

  float4 w0 = {0.f, 0.f, 0.f, 0.f}, w1 = {0.f, 0.f, 0.f, 0.f};
  float4 m0 = {0.f, 0.f, 0.f, 0.f}, m1 = {0.f, 0.f, 0.f, 0.f};

  // Pipeline prologue: chunk 0 -> LDS buf0, chunk 1 -> regs.
  load_stage(0);
  write_stage(0);
  load_stage(T_);

  for (int c = 0; c < NCH; ++c) {
    // Stage chunk c+1 into the buffer not being read this iteration
    // (its reader, iteration c-1, already issued all its ds_reads;
    // per-wave LDS ops are in-order).
    write_stage((c + 1) & 1);
    // Fire global loads for chunk c+2 (consumed next iteration).
    load_stage((c + 2) * T_);
    __builtin_amdgcn_sched_barrier(0);  // keep loads ahead of the compute body

    const int bsel = c & 1;
    float* yp = Yp + (size_t)c * T_ * D_;
    Frag f = read_frag(bsel, 0);

#pragma unroll
    for (int t = 0; t < T_; ++t) {
      Frag fn = read_frag(bsel, (t + 1) & (T_ - 1));  // prefetch next step

      // ---- resid = w·k - v  (serial chain) ----
      float a0 = w0.x * f.k0.x;
      float a1 = w0.y * f.k0.y;
      float a2 = w0.z * f.k0.z;
      float a3 = w0.w * f.k0.w;
      a0 = fmaf(w1.x, f.k1.x, a0);
      a1 = fmaf(w1.y, f.k1.y, a1);
      a2 = fmaf(w1.z, f.k1.z, a2);
      a3 = fmaf(w1.w, f.k1.w, a3);
      float dot = row16_allsum((a0 + a1) + (a2 + a3));
      float s = C_S * (dot - f.v);

      // ---- m̂ = β m̂ + s k ; w = A w + m̂ ----
      m0.x = fmaf(BETA_, m0.x, s * f.k0.x);
      m0.y = fmaf(BETA_, m0.y, s * f.k0.y);
      m0.z = fmaf(BETA_, m0.z, s * f.k0.z);
      m0.w = fmaf(BETA_, m0.w, s * f.k0.w);
      m1.x = fmaf(BETA_, m1.x, s * f.k1.x);
      m1.y = fmaf(BETA_, m1.y, s * f.k1.y);
      m1.z = fmaf(BETA_, m1.z, s * f.k1.z);
      m1.w = fmaf(BETA_, m1.w, s * f.k1.w);

      w0.x = fmaf(A_, w0.x, m0.x);
      w0.y = fmaf(A_, w0.y, m0.y);
      w0.z = fmaf(A_, w0.z, m0.z);
      w0.w = fmaf(A_, w0.w, m0.w);
      w1.x = fmaf(A_, w1.x, m1.x);
      w1.y = fmaf(A_, w1.y, m1.y);
      w1.z = fmaf(A_, w1.z, m1.z);
      w1.w = fmaf(A_, w1.w, m1.w);

      // ---- y = w·q  (off the serial chain) ----
      float b0 = w0.x * f.q0.x;
      float b1 = w0.y * f.q0.y;
      float b2 = w0.z * f.q0.z;
      float b3 = w0.w * f.q0.w;
      b0 = fmaf(w1.x, f.q1.x, b0);
      b1 = fmaf(w1.y, f.q1.y, b1);
      b2 = fmaf(w1.z, f.q1.z, b2);
      b3 = fmaf(w1.w, f.q1.w, b3);
      float y = row16_allsum((b0 + b1) + (b2 + b3));

      if (do_store) yp[(size_t)t * D_] = y;
      f = fn;
    }
  }
}

extern "C" void kernel_launch(void* const* d_in, const int* in_sizes, int n_in,
                              void* d_out, int out_size, void* d_ws, size_t ws_size,
                              hipStream_t stream) {
  const float* Q = (const float*)d_in[0];
  const float* K = (const float*)d_in[1];
  const float* V = (const float*)d_in[2];
  float* Y = (float*)d_out;
  dim3 grid(512), block(64);
  hipLaunchKernelGGL(TitansMemory_188978561365_kernel, grid, block, 0, stream,
                     Q, K, V, Y);
}

// Round 3
// 1679.891 us; speedup vs baseline: 1.8165x; 1.3033x over previous
//
#include <hip/hip_runtime.h>

// TitansMemory: per-row delta-rule-with-momentum scan. B=16, L=8192, DK=DV=128.
// 2048 independent rows (b,v):
//   s = C_S*(w·k - v) ; m̂ = β m̂ + s k   (m̂ = -lr m, C_S = -2 lr (1-β))
//   w = (1-α) w + m̂   ; y = w·q
// Mapping: 16 lanes/row (one DPP row), 8 cols/lane, 4 rows/wave, 512 waves =
// 512 single-wave blocks (2 waves/CU — occupancy is capped by job count, so
// VGPRs are free: __launch_bounds__(64,1)).
// Memory: NO LDS. k/q/v fragments load straight from global (L1/L2-hot: the
// 32 waves of a batch share the same rows; each load instr touches only 16
// distinct 16B chunks). 8-deep register prefetch, pinned by sched_barrier(0)
// fences around every step body so the scheduler cannot collapse the issue
// distance (round-1 failure mode). Elementwise math on float2 ext-vectors to
// get v_pk_fma_f32 (CDNA packed fp32, full rate). Y stores batched 16 steps
// per store via DPP-allsum + per-lane cndmask select (lane c16 keeps t≡c16),
// stored nontemporally to keep Y out of L2.

#define B_ 16
#define L_ 8192
#define D_ 128
#define PF 8  // prefetch depth == inner unroll

typedef __attribute__((ext_vector_type(2))) float f2;

constexpr float A_    = 0.98f;
constexpr float BETA_ = 0.9f;
constexpr float C_S   = -(2.0f * 0.1f * 0.1f);

template <int CTRL>
__device__ __forceinline__ float dpp_add(float x) {
  int y = __builtin_amdgcn_update_dpp(0, __float_as_int(x), CTRL, 0xF, 0xF, true);
  return x + __int_as_float(y);
}

// Sum across each 16-lane DPP row; every lane of the row gets the total.
__device__ __forceinline__ float row16_allsum(float x) {
  x = dpp_add<0x121>(x);  // row_ror:1
  x = dpp_add<0x122>(x);  // row_ror:2
  x = dpp_add<0x124>(x);  // row_ror:4
  x = dpp_add<0x128>(x);  // row_ror:8
  return x;
}

struct Frag {
  float4 ka, kb, qa, qb;  // k cols 0..3 / 4..7, q cols 0..3 / 4..7 (per lane)
  float v;
};

__global__ __launch_bounds__(64, 1)
void TitansMemory_188978561365_kernel(const float* __restrict__ Q,
                                      const float* __restrict__ K,
                                      const float* __restrict__ V,
                                      float* __restrict__ Y) {
  const int lane    = threadIdx.x;       // 0..63
  const int wid     = blockIdx.x;        // 0..511
  const int batch   = wid >> 5;          // 32 waves per batch
  const int rowbase = (wid & 31) << 2;   // 4 rows per wave
  const int rl      = lane >> 4;         // row within wave (DPP row id)
  const int c16     = lane & 15;         // column group
  const int col0    = c16 << 3;          // 8 cols per lane

  const size_t bbase = (size_t)batch * (size_t)L_ * D_;
  const float* Kp = K + bbase + col0;
  const float* Qp = Q + bbase + col0;
  const float* Vp = V + bbase + rowbase + rl;
  // lane (rl,c16) stores y(row=rowbase+rl, t=16*w+c16) at window w:
  float* Yst = Y + bbase + (size_t)c16 * D_ + rowbase + rl;

  auto ldfrag = [&](int t) -> Frag {
    const float* kp = Kp + (size_t)t * D_;
    const float* qp = Qp + (size_t)t * D_;
    Frag f;
    f.ka = *(const float4*)(kp);
    f.kb = *(const float4*)(kp + 4);
    f.qa = *(const float4*)(qp);
    f.qb = *(const float4*)(qp + 4);
    f.v  = Vp[(size_t)t * D_];
    return f;
  };

  const f2 av = {A_, A_};
  const f2 bv = {BETA_, BETA_};

  f2 w0 = {0.f, 0.f}, w1 = {0.f, 0.f}, w2 = {0.f, 0.f}, w3 = {0.f, 0.f};
  f2 m0 = {0.f, 0.f}, m1 = {0.f, 0.f}, m2 = {0.f, 0.f}, m3 = {0.f, 0.f};
  float ylane = 0.f;

  // One scan step. t is the (dynamic) step index; tm = t & 15 passed so the
  // compiler folds the compare per unrolled body.
  auto step = [&](const Frag& f, int t) {
    f2 k0 = {f.ka.x, f.ka.y}, k1 = {f.ka.z, f.ka.w};
    f2 k2 = {f.kb.x, f.kb.y}, k3 = {f.kb.z, f.kb.w};
    f2 q0 = {f.qa.x, f.qa.y}, q1 = {f.qa.z, f.qa.w};
    f2 q2 = {f.qb.x, f.qb.y}, q3 = {f.qb.z, f.qb.w};

    // ---- dot = w·k (serial chain), packed fp32 ----
    f2 d = w0 * k0;
    d = __builtin_elementwise_fma(w1, k1, d);
    d = __builtin_elementwise_fma(w2, k2, d);
    d = __builtin_elementwise_fma(w3, k3, d);
    float dot = row16_allsum(d.x + d.y);
    float nv = (-C_S) * f.v;              // off-chain
    float s  = fmaf(C_S, dot, nv);
    f2 s2 = {s, s};

    // ---- m̂ = β m̂ + s k ; w = A w + m̂ ----
    m0 = __builtin_elementwise_fma(bv, m0, s2 * k0);
    m1 = __builtin_elementwise_fma(bv, m1, s2 * k1);
    m2 = __builtin_elementwise_fma(bv, m2, s2 * k2);
    m3 = __builtin_elementwise_fma(bv, m3, s2 * k3);
    w0 = __builtin_elementwise_fma(av, w0, m0);
    w1 = __builtin_elementwise_fma(av, w1, m1);
    w2 = __builtin_elementwise_fma(av, w2, m2);
    w3 = __builtin_elementwise_fma(av, w3, m3);

    // ---- y = w·q (off the serial chain) ----
    f2 e = w0 * q0;
    e = __builtin_elementwise_fma(w1, q1, e);
    e = __builtin_elementwise_fma(w2, q2, e);
    e = __builtin_elementwise_fma(w3, q3, e);
    float y = row16_allsum(e.x + e.y);

    // every lane of the 16-group holds y_t; lane c16 keeps t ≡ c16 (mod 16)
    const int tm = t & 15;
    ylane = (c16 == tm) ? y : ylane;
    if (tm == 15) {
      __builtin_nontemporal_store(ylane, Yst + (size_t)(t >> 4) * (16 * D_));
    }
  };

  // Prologue: fill the 8-deep prefetch pipeline.
  Frag fr[PF];
#pragma unroll
  for (int j = 0; j < PF; ++j) fr[j] = ldfrag(j);

  // Main loop: compute step t from fr[j], then reload fr[j] for t+PF.
  // sched_barrier(0) fences pin the issue distance (no cross-body motion).
  for (int tb = 0; tb < L_ - PF; tb += PF) {
#pragma unroll
    for (int j = 0; j < PF; ++j) {
      const int t = tb + j;
      __builtin_amdgcn_sched_barrier(0);
      step(fr[j], t);
      __builtin_amdgcn_sched_barrier(0);
      fr[j] = ldfrag(t + PF);
      __builtin_amdgcn_sched_barrier(0);
    }
  }
  // Epilogue: last PF steps, no reloads.
#pragma unroll
  for (int j = 0; j < PF; ++j) {
    __builtin_amdgcn_sched_barrier(0);
    step(fr[j], L_ - PF + j);
  }
}

extern "C" void kernel_launch(void* const* d_in, const int* in_sizes, int n_in,
                              void* d_out, int out_size, void* d_ws, size_t ws_size,
                              hipStream_t stream) {
  const float* Q = (const float*)d_in[0];
  const float* K = (const float*)d_in[1];
  const float* V = (const float*)d_in[2];
  float* Y = (float*)d_out;
  dim3 grid(512), block(64);
  hipLaunchKernelGGL(TitansMemory_188978561365_kernel, grid, block, 0, stream,
                     Q, K, V, Y);
}

// Round 5
// 1530.923 us; speedup vs baseline: 1.9933x; 1.0973x over previous
//
#include <hip/hip_runtime.h>

// TitansMemory: per-row delta-rule-with-momentum scan. B=16, L=8192, DK=DV=128.
// 2048 independent rows (b,v):
//   s = C_S*(w·k - v) ; m̂ = β m̂ + s k   (m̂ = -lr m, C_S = -2 lr (1-β))
//   w = (1-α) w + m̂   ; y = w·q
// Mapping (round 5): ONE row per wave, 2 cols/lane (f2), 2048 single-wave
// blocks = 8 waves/CU = 2 waves/SIMD -> hardware wave interleaving hides both
// memory latency and the DPP-chain latency (rounds 1-3 at 512 waves had 1
// wave per 2 SIMDs: every bubble was wall time).
// Reduction: 64-lane sum via DPP row_ror:1,2,4,8 + row_bcast:15 + row_bcast:31
// (total lands in lane 63) + v_readlane -> wave-uniform scalar in SGPR.
// s feeds the packed update as a broadcast; y is kept per-lane via
// v_cndmask (lane == t&63) and stored once per 64 steps.
// Memory: A/B ping-pong register frag buffers (8+8 deep, cross-backedge data
// dependence = uncollapsible distance, proven in round 2), no LDS.

#define B_ 16
#define L_ 8192
#define D_ 128
#define CH 8  // half-chunk depth (A/B buffers)

typedef __attribute__((ext_vector_type(2))) float f2;

constexpr float A_    = 0.98f;
constexpr float BETA_ = 0.9f;
constexpr float C_S   = -(2.0f * 0.1f * 0.1f);  // -2*lr*(1-beta) = -0.02

template <int CTRL>
__device__ __forceinline__ float dpp_add(float x) {
  int y = __builtin_amdgcn_update_dpp(0, __float_as_int(x), CTRL, 0xF, 0xF, true);
  return x + __int_as_float(y);
}

// Full-wave64 sum; returns the total (read from lane 63) as a uniform scalar.
__device__ __forceinline__ float wave_sum_uniform(float x) {
  x = dpp_add<0x121>(x);  // row_ror:1
  x = dpp_add<0x122>(x);  // row_ror:2
  x = dpp_add<0x124>(x);  // row_ror:4
  x = dpp_add<0x128>(x);  // row_ror:8  -> each 16-row holds its row-sum
  x = dpp_add<0x142>(x);  // row_bcast:15 -> rows 1,3 += rows 0,2
  x = dpp_add<0x143>(x);  // row_bcast:31 -> row 3 += (r0+r1); lane63 = total
  return __int_as_float(__builtin_amdgcn_readlane(__float_as_int(x), 63));
}

struct Frag {
  f2 k, q;   // this lane's 2 cols of k_t, q_t
  float v;   // v[t, row] (wave-uniform broadcast load)
};

__global__ __launch_bounds__(64, 2)
void TitansMemory_188978561365_kernel(const float* __restrict__ Q,
                                      const float* __restrict__ K,
                                      const float* __restrict__ V,
                                      float* __restrict__ Y) {
  const int lane  = threadIdx.x;        // 0..63
  const int wid   = blockIdx.x;         // 0..2047
  const int batch = wid >> 7;           // 128 rows per batch
  const int row   = wid & 127;

  const size_t bbase = (size_t)batch * (size_t)L_ * D_;
  const float* Kp = K + bbase + lane * 2;
  const float* Qp = Q + bbase + lane * 2;
  const float* Vp = V + bbase + row;
  float*       Yp = Y + bbase + row;    // + (t-window*64 + lane)*D_

  auto ld = [&](int t) -> Frag {
    int tc = (t < L_) ? t : (L_ - 1);   // clamp tail prefetch
    Frag f;
    f.k = *(const f2*)(Kp + (size_t)tc * D_);
    f.q = *(const f2*)(Qp + (size_t)tc * D_);
    f.v = Vp[(size_t)tc * D_];
    return f;
  };

  const f2 av = {A_, A_};
  const f2 bv = {BETA_, BETA_};

  f2 w = {0.f, 0.f}, m = {0.f, 0.f};
  float yl = 0.f;

  auto step = [&](const Frag& f, int t) {
    // ---- dot = w·k  (serial chain) ----
    f2 d = w * f.k;
    float dot = wave_sum_uniform(d.x + d.y);
    float vneg = (-C_S) * f.v;              // off-chain
    float s = fmaf(C_S, dot, vneg);
    f2 s2 = {s, s};

    // ---- m̂ = β m̂ + s k ; w = A w + m̂  (packed f32) ----
    m = __builtin_elementwise_fma(s2, f.k, bv * m);
    w = __builtin_elementwise_fma(av, w, m);

    // ---- y = w·q  (off the serial chain) ----
    f2 e = w * f.q;
    float y = wave_sum_uniform(e.x + e.y);

    // lane (t&63) keeps y_t (y is wave-uniform); one store per 64 steps.
    yl = (lane == (t & 63)) ? y : yl;
    if ((t & 63) == 63) {
      Yp[(size_t)((t & ~63) + lane) * D_] = yl;
    }
  };

  // Prologue: fill both frag buffers (steps 0..15).
  Frag fa[CH], fb[CH];
#pragma unroll
  for (int j = 0; j < CH; ++j) fa[j] = ld(j);
#pragma unroll
  for (int j = 0; j < CH; ++j) fb[j] = ld(CH + j);

  for (int tb = 0; tb < L_; tb += 2 * CH) {
#pragma unroll
    for (int j = 0; j < CH; ++j) step(fa[j], tb + j);
#pragma unroll
    for (int j = 0; j < CH; ++j) fa[j] = ld(tb + 2 * CH + j);
    __builtin_amdgcn_sched_barrier(0);  // loads stay ahead of the B-half
#pragma unroll
    for (int j = 0; j < CH; ++j) step(fb[j], tb + CH + j);
#pragma unroll
    for (int j = 0; j < CH; ++j) fb[j] = ld(tb + 3 * CH + j);
    __builtin_amdgcn_sched_barrier(0);  // loads stay ahead of the backedge
  }
}

extern "C" void kernel_launch(void* const* d_in, const int* in_sizes, int n_in,
                              void* d_out, int out_size, void* d_ws, size_t ws_size,
                              hipStream_t stream) {
  const float* Q = (const float*)d_in[0];
  const float* K = (const float*)d_in[1];
  const float* V = (const float*)d_in[2];
  float* Y = (float*)d_out;
  dim3 grid(2048), block(64);
  hipLaunchKernelGGL(TitansMemory_188978561365_kernel, grid, block, 0, stream,
                     Q, K, V, Y);
}